// Round 4
// baseline (1600.846 us; speedup 1.0000x reference)
//
#include <hip/hip_runtime.h>

#define MDIM 8192
#define NDIM 16384
#define KDIM 4096

typedef __bf16 bf16x8 __attribute__((ext_vector_type(8)));
typedef float f32x4 __attribute__((ext_vector_type(4)));
typedef float f32x16 __attribute__((ext_vector_type(16)));

__device__ __forceinline__ unsigned short f2bf(float f) {
  __bf16 h = (__bf16)f;
  return __builtin_bit_cast(unsigned short, h);
}

__device__ __forceinline__ void gload_lds16(const void* g, void* l) {
  __builtin_amdgcn_global_load_lds(
      (const __attribute__((address_space(1))) unsigned int*)g,
      (__attribute__((address_space(3))) unsigned int*)l, 16, 0, 0);
}

// ---------- pass 1a: fp32 -> bf16 ----------
__global__ __launch_bounds__(256) void cvt_a_kernel(const float* __restrict__ a,
                                                    unsigned short* __restrict__ o,
                                                    long long n) {
  long long i = ((long long)blockIdx.x * 256 + threadIdx.x) * 8;
  const long long stride = (long long)gridDim.x * 2048;
  for (; i < n; i += stride) {
    float4 x = *(const float4*)(a + i);
    float4 y = *(const float4*)(a + i + 4);
    union { unsigned short u[8]; uint4 v; } r;
    r.u[0] = f2bf(x.x); r.u[1] = f2bf(x.y); r.u[2] = f2bf(x.z); r.u[3] = f2bf(x.w);
    r.u[4] = f2bf(y.x); r.u[5] = f2bf(y.y); r.u[6] = f2bf(y.z); r.u[7] = f2bf(y.w);
    *(uint4*)(o + i) = r.v;
  }
}

// ---------- pass 1b: int32 (int8 values) -> bf16 (exact, |w|<=127) ----------
__global__ __launch_bounds__(256) void cvt_w_kernel(const int* __restrict__ w,
                                                    unsigned short* __restrict__ o,
                                                    long long n) {
  long long i = ((long long)blockIdx.x * 256 + threadIdx.x) * 8;
  const long long stride = (long long)gridDim.x * 2048;
  for (; i < n; i += stride) {
    int4 x = *(const int4*)(w + i);
    int4 y = *(const int4*)(w + i + 4);
    union { unsigned short u[8]; uint4 v; } r;
    r.u[0] = f2bf((float)x.x); r.u[1] = f2bf((float)x.y);
    r.u[2] = f2bf((float)x.z); r.u[3] = f2bf((float)x.w);
    r.u[4] = f2bf((float)y.x); r.u[5] = f2bf((float)y.y);
    r.u[6] = f2bf((float)y.z); r.u[7] = f2bf((float)y.w);
    *(uint4*)(o + i) = r.v;
  }
}

// ---------- pass 2: 256x128 tile, BK=32, 3-buf (72 KiB -> 2 blocks/CU),
// 8 waves of 64x64 via mfma_f32_32x32x16_bf16, counted vmcnt(3), nt stores ----
// Buf layout (24576 B each): [A: 256 rows x 32 k = 16 KB][B: 128 rows x 32 k = 8 KB]
// Row = 64 B = 4 slots of 16 B; phys slot = logical_slot ^ (row & 3)  (conflict-
// free: 8 words/bank on every ds_read_b128). gl_lds dest linear; inverse swizzle
// applied to per-lane GLOBAL source (rule: both-sides-or-neither).
__global__ __launch_bounds__(512, 4) void gemm_bf16_ov(
    const unsigned short* __restrict__ Ab, const unsigned short* __restrict__ Wb,
    const float* __restrict__ sc, const float* __restrict__ bi,
    float* __restrict__ out) {
  __shared__ char sm[3 * 24576];
  const int tid = threadIdx.x;
  const int lane = tid & 63;
  const int wv = tid >> 6;
  const int l31 = lane & 31;
  const int l32 = lane >> 5;
  // XCD-aware swizzle: 4096 blocks % 8 == 0
  const int wg = (blockIdx.x & 7) * 512 + (blockIdx.x >> 3);
  const int bm = (wg & 31) << 8;   // M/256 = 32 (fast-varying: share B-panel)
  const int bn = (wg >> 5) << 7;   // N/128 = 128
  const int wr = wv & 3;           // 0..3 -> A rows wr*64..+64
  const int wcn = wv >> 2;         // 0..1 -> B cols wcn*64..+64

  // staging source: thread t covers LDS chunk t (16 B) of each 8 KB region.
  // LDS row = t>>2, phys slot = t&3 -> logical k-slot = (t&3)^((t>>2)&3).
  const int ksl = (((tid & 3) ^ ((tid >> 2) & 3)) << 3);
  const int srow = tid >> 2;  // 0..127
  const unsigned short* pa = Ab + (long long)(bm + srow) * KDIM + ksl;  // A rows 0-127
  const unsigned short* pa1 = pa + (long long)128 * KDIM;               // A rows 128-255
  const unsigned short* pb = Wb + (long long)(bn + srow) * KDIM + ksl;  // B rows 0-127
  const int dA0 = wv * 1024;          // byte offsets of this wave's gl_lds dests
  const int dA1 = 8192 + wv * 1024;
  const int dB = 16384 + wv * 1024;

  // tile-invariant swizzled frag byte-offsets within a buffer
  int aOff[2][2], bOff[2][2];
#pragma unroll
  for (int mb = 0; mb < 2; ++mb)
#pragma unroll
    for (int kh = 0; kh < 2; ++kh) {
      const int row = wr * 64 + mb * 32 + l31;
      aOff[mb][kh] = row * 64 + (((kh * 2 + l32) ^ (row & 3)) << 4);
    }
#pragma unroll
  for (int nb = 0; nb < 2; ++nb)
#pragma unroll
    for (int kh = 0; kh < 2; ++kh) {
      const int row = wcn * 64 + nb * 32 + l31;
      bOff[nb][kh] = 16384 + row * 64 + (((kh * 2 + l32) ^ (row & 3)) << 4);
    }

  f32x16 acc[2][2] = {};

  char* bR = &sm[0];      // read buf  (tile t)
  char* bN = &sm[24576];  // next buf  (tile t+1)
  char* bS = &sm[49152];  // stage buf (tile t+2)

  // prologue: stage tiles 0,1; wait tile 0 (vmcnt(3): tile-1's 3 still out)
  gload_lds16(pa, bR + dA0);
  gload_lds16(pa1, bR + dA1);
  gload_lds16(pb, bR + dB);
  gload_lds16(pa + 32, bN + dA0);
  gload_lds16(pa1 + 32, bN + dA1);
  gload_lds16(pb + 32, bN + dB);
  asm volatile("s_waitcnt vmcnt(3)" ::: "memory");
  __builtin_amdgcn_s_barrier();

  for (int t = 0; t < 128; ++t) {
    if (t <= 125) {  // stage tile t+2 into bS (freed by barrier at end of t-1)
      const int kt = t * 32 + 64;
      gload_lds16(pa + kt, bS + dA0);
      gload_lds16(pa1 + kt, bS + dA1);
      gload_lds16(pb + kt, bS + dB);
    }
    __builtin_amdgcn_s_setprio(1);
#pragma unroll
    for (int kh = 0; kh < 2; ++kh) {
      bf16x8 aF0 = *(const bf16x8*)(bR + aOff[0][kh]);
      bf16x8 aF1 = *(const bf16x8*)(bR + aOff[1][kh]);
      bf16x8 bF0 = *(const bf16x8*)(bR + bOff[0][kh]);
      bf16x8 bF1 = *(const bf16x8*)(bR + bOff[1][kh]);
      acc[0][0] = __builtin_amdgcn_mfma_f32_32x32x16_bf16(aF0, bF0, acc[0][0], 0, 0, 0);
      acc[0][1] = __builtin_amdgcn_mfma_f32_32x32x16_bf16(aF0, bF1, acc[0][1], 0, 0, 0);
      acc[1][0] = __builtin_amdgcn_mfma_f32_32x32x16_bf16(aF1, bF0, acc[1][0], 0, 0, 0);
      acc[1][1] = __builtin_amdgcn_mfma_f32_32x32x16_bf16(aF1, bF1, acc[1][1], 0, 0, 0);
    }
    __builtin_amdgcn_s_setprio(0);
    if (t < 126) {
      asm volatile("s_waitcnt vmcnt(3)" ::: "memory");  // tile t+1 resident
    } else if (t == 126) {
      asm volatile("s_waitcnt vmcnt(0)" ::: "memory");
    }
    if (t < 127) __builtin_amdgcn_s_barrier();
    char* tmp = bR; bR = bN; bN = bS; bS = tmp;  // rotate
  }

  // epilogue: 32x32 C/D layout col = lane&31, row = (r&3) + 8*(r>>2) + 4*(lane>>5)
  float sv[2], bv[2];
#pragma unroll
  for (int nb = 0; nb < 2; ++nb) {
    const int c = bn + wcn * 64 + nb * 32 + l31;
    sv[nb] = sc[c];
    bv[nb] = bi[c];
  }
#pragma unroll
  for (int mb = 0; mb < 2; ++mb) {
    const int rb = bm + wr * 64 + mb * 32 + l32 * 4;
#pragma unroll
    for (int nb = 0; nb < 2; ++nb) {
      const int c = bn + wcn * 64 + nb * 32 + l31;
      const float s = sv[nb], b = bv[nb];
#pragma unroll
      for (int r = 0; r < 16; ++r) {
        const long long row = rb + (r & 3) + 8 * (r >> 2);
        __builtin_nontemporal_store(acc[mb][nb][r] * s + b,
                                    out + row * NDIM + c);
      }
    }
  }
}

// ---------- fallback: inline-convert reg-staged GEMM (if ws too small) ----------
__global__ __launch_bounds__(256, 2) void gemm_inline(
    const float* __restrict__ A, const int* __restrict__ W,
    const float* __restrict__ sc, const float* __restrict__ bi,
    float* __restrict__ out) {
  __shared__ unsigned short As[128 * 72];
  __shared__ unsigned short Bs[128 * 72];
  const int tid = threadIdx.x;
  const int lane = tid & 63;
  const int wv = tid >> 6;
  const int wg = (blockIdx.x & 7) * 1024 + (blockIdx.x >> 3);
  const int bm = (wg & 63) * 128;
  const int bn = (wg >> 6) * 128;
  const int wr = (wv >> 1) * 64;
  const int wc = (wv & 1) * 64;
  const int r16 = lane & 15;
  const int g4 = lane >> 4;

  f32x4 acc[4][4] = {};

  const int srow = tid >> 4;
  const int sc4 = (tid & 15) << 2;
  const float* aPtr = A + (long long)(bm + srow) * KDIM + sc4;
  const int* wPtr = W + (long long)(bn + srow) * KDIM + sc4;

  for (int kt = 0; kt < KDIM; kt += 64) {
    float4 av[8];
    int4 wv4[8];
#pragma unroll
    for (int j = 0; j < 8; ++j)
      av[j] = *(const float4*)(aPtr + (long long)j * 16 * KDIM + kt);
#pragma unroll
    for (int j = 0; j < 8; ++j)
      wv4[j] = *(const int4*)(wPtr + (long long)j * 16 * KDIM + kt);
    __syncthreads();
#pragma unroll
    for (int j = 0; j < 8; ++j) {
      ushort4 u;
      u.x = f2bf(av[j].x); u.y = f2bf(av[j].y);
      u.z = f2bf(av[j].z); u.w = f2bf(av[j].w);
      *(ushort4*)&As[(srow + j * 16) * 72 + sc4] = u;
    }
#pragma unroll
    for (int j = 0; j < 8; ++j) {
      ushort4 u;
      u.x = f2bf((float)wv4[j].x); u.y = f2bf((float)wv4[j].y);
      u.z = f2bf((float)wv4[j].z); u.w = f2bf((float)wv4[j].w);
      *(ushort4*)&Bs[(srow + j * 16) * 72 + sc4] = u;
    }
    __syncthreads();
#pragma unroll
    for (int ks = 0; ks < 2; ++ks) {
      bf16x8 aF[4], bF[4];
      const int kofs = ks * 32 + g4 * 8;
#pragma unroll
      for (int m2 = 0; m2 < 4; ++m2)
        aF[m2] = *(const bf16x8*)&As[(wr + m2 * 16 + r16) * 72 + kofs];
#pragma unroll
      for (int n2 = 0; n2 < 4; ++n2)
        bF[n2] = *(const bf16x8*)&Bs[(wc + n2 * 16 + r16) * 72 + kofs];
#pragma unroll
      for (int m2 = 0; m2 < 4; ++m2)
#pragma unroll
        for (int n2 = 0; n2 < 4; ++n2)
          acc[m2][n2] = __builtin_amdgcn_mfma_f32_16x16x32_bf16(
              aF[m2], bF[n2], acc[m2][n2], 0, 0, 0);
    }
  }

  float sv[4], bv[4];
#pragma unroll
  for (int n2 = 0; n2 < 4; ++n2) {
    const int c = bn + wc + n2 * 16 + r16;
    sv[n2] = sc[c];
    bv[n2] = bi[c];
  }
#pragma unroll
  for (int m2 = 0; m2 < 4; ++m2) {
    const int row0 = bm + wr + m2 * 16 + g4 * 4;
#pragma unroll
    for (int n2 = 0; n2 < 4; ++n2) {
      const int c = bn + wc + n2 * 16 + r16;
      float* op = out + (long long)row0 * NDIM + c;
#pragma unroll
      for (int r = 0; r < 4; ++r)
        op[(long long)r * NDIM] = acc[m2][n2][r] * sv[n2] + bv[n2];
    }
  }
}

extern "C" void kernel_launch(void* const* d_in, const int* in_sizes, int n_in,
                              void* d_out, int out_size, void* d_ws, size_t ws_size,
                              hipStream_t stream) {
  const float* A = (const float*)d_in[0];
  const int* W = (const int*)d_in[1];
  const float* sc = (const float*)d_in[2];
  const float* bi = (const float*)d_in[3];
  float* out = (float*)d_out;

  const long long nA = (long long)MDIM * KDIM;
  const long long nW = (long long)NDIM * KDIM;
  const size_t needA = (size_t)nA * sizeof(unsigned short);
  const size_t needW = (size_t)nW * sizeof(unsigned short);

  if (d_ws != nullptr && ws_size >= needA + needW) {
    unsigned short* Ab = (unsigned short*)d_ws;
    unsigned short* Wb = (unsigned short*)((char*)d_ws + needA);
    cvt_a_kernel<<<2048, 256, 0, stream>>>(A, Ab, nA);
    cvt_w_kernel<<<4096, 256, 0, stream>>>(W, Wb, nW);
    gemm_bf16_ov<<<4096, 512, 0, stream>>>(Ab, Wb, sc, bi, out);
  } else {
    gemm_inline<<<8192, 256, 0, stream>>>(A, W, sc, bi, out);
  }
}

// Round 5
// 1247.599 us; speedup vs baseline: 1.2831x; 1.2831x over previous
//
#include <hip/hip_runtime.h>

#define MDIM 8192
#define NDIM 16384
#define KDIM 4096

typedef __bf16 bf16x8 __attribute__((ext_vector_type(8)));
typedef float f32x4 __attribute__((ext_vector_type(4)));
typedef float f32x16 __attribute__((ext_vector_type(16)));

__device__ __forceinline__ unsigned short f2bf(float f) {
  __bf16 h = (__bf16)f;
  return __builtin_bit_cast(unsigned short, h);
}

__device__ __forceinline__ void gload_lds16(const void* g, void* l) {
  __builtin_amdgcn_global_load_lds(
      (const __attribute__((address_space(1))) unsigned int*)g,
      (__attribute__((address_space(3))) unsigned int*)l, 16, 0, 0);
}

// ---------- pass 1a: fp32 -> bf16 ----------
__global__ __launch_bounds__(256) void cvt_a_kernel(const float* __restrict__ a,
                                                    unsigned short* __restrict__ o,
                                                    long long n) {
  long long i = ((long long)blockIdx.x * 256 + threadIdx.x) * 8;
  const long long stride = (long long)gridDim.x * 2048;
  for (; i < n; i += stride) {
    float4 x = *(const float4*)(a + i);
    float4 y = *(const float4*)(a + i + 4);
    union { unsigned short u[8]; uint4 v; } r;
    r.u[0] = f2bf(x.x); r.u[1] = f2bf(x.y); r.u[2] = f2bf(x.z); r.u[3] = f2bf(x.w);
    r.u[4] = f2bf(y.x); r.u[5] = f2bf(y.y); r.u[6] = f2bf(y.z); r.u[7] = f2bf(y.w);
    *(uint4*)(o + i) = r.v;
  }
}

// ---------- pass 1b: int32 (int8 values) -> bf16 (exact, |w|<=127) ----------
__global__ __launch_bounds__(256) void cvt_w_kernel(const int* __restrict__ w,
                                                    unsigned short* __restrict__ o,
                                                    long long n) {
  long long i = ((long long)blockIdx.x * 256 + threadIdx.x) * 8;
  const long long stride = (long long)gridDim.x * 2048;
  for (; i < n; i += stride) {
    int4 x = *(const int4*)(w + i);
    int4 y = *(const int4*)(w + i + 4);
    union { unsigned short u[8]; uint4 v; } r;
    r.u[0] = f2bf((float)x.x); r.u[1] = f2bf((float)x.y);
    r.u[2] = f2bf((float)x.z); r.u[3] = f2bf((float)x.w);
    r.u[4] = f2bf((float)y.x); r.u[5] = f2bf((float)y.y);
    r.u[6] = f2bf((float)y.z); r.u[7] = f2bf((float)y.w);
    *(uint4*)(o + i) = r.v;
  }
}

// ---------- pass 2: 256x128 tile, BK=32, 3-buf (72 KiB -> 2 blocks/CU),
// 8 waves of 64x64 via mfma_f32_32x32x16_bf16, counted vmcnt(3), nt stores.
// Swizzle (VERIFIED conflict-free in rounds 2/3, 0 conflicts): phys 16B-slot =
// logical_slot ^ ((row>>1)&3). 8 consecutive rows then cover all 32 banks per
// 8-lane group of a ds_read_b128. gl_lds dest linear; inverse swizzle applied
// to the per-lane GLOBAL source (both-sides-or-neither rule).
__global__ __launch_bounds__(512, 4) void gemm_bf16_ov(
    const unsigned short* __restrict__ Ab, const unsigned short* __restrict__ Wb,
    const float* __restrict__ sc, const float* __restrict__ bi,
    float* __restrict__ out) {
  __shared__ char sm[3 * 24576];
  const int tid = threadIdx.x;
  const int lane = tid & 63;
  const int wv = tid >> 6;
  const int l31 = lane & 31;
  const int l32 = lane >> 5;
  // 2D XCD chunking: XCD c owns an 8(bm) x 64(bn) tile rectangle, bm-fast.
  // Co-resident ~64 blocks/XCD stream the same k-slab of 8 A- + 8 B-panels.
  const int c = blockIdx.x & 7;
  const int l = blockIdx.x >> 3;  // 0..511
  const int bm = (((c & 3) << 3) + (l & 7)) << 8;    // 32 tiles * 256 rows
  const int bn = (((c >> 1) & ~1) << 5 | (l >> 3)) << 7;  // ((c>>2)*64 + l>>3)*128
  const int wr = wv & 3;           // 0..3 -> A rows wr*64..+64
  const int wcn = wv >> 2;         // 0..1 -> B cols wcn*64..+64

  // staging source: thread t covers LDS chunk t (16 B) of each 8 KB region.
  // LDS row = t>>2, phys slot = t&3 -> logical k-slot = (t&3) ^ ((t>>3)&3).
  const int ksl = (((tid & 3) ^ ((tid >> 3) & 3)) << 3);
  const int srow = tid >> 2;  // 0..127
  const unsigned short* pa = Ab + (long long)(bm + srow) * KDIM + ksl;  // A rows 0-127
  const unsigned short* pa1 = pa + (long long)128 * KDIM;               // A rows 128-255
  const unsigned short* pb = Wb + (long long)(bn + srow) * KDIM + ksl;  // B rows 0-127
  const int dA0 = wv * 1024;          // byte offsets of this wave's gl_lds dests
  const int dA1 = 8192 + wv * 1024;
  const int dB = 16384 + wv * 1024;

  // tile-invariant swizzled frag byte-offsets within a buffer
  int aOff[2][2], bOff[2][2];
#pragma unroll
  for (int mb = 0; mb < 2; ++mb)
#pragma unroll
    for (int kh = 0; kh < 2; ++kh) {
      const int row = wr * 64 + mb * 32 + l31;
      aOff[mb][kh] = row * 64 + (((kh * 2 + l32) ^ ((row >> 1) & 3)) << 4);
    }
#pragma unroll
  for (int nb = 0; nb < 2; ++nb)
#pragma unroll
    for (int kh = 0; kh < 2; ++kh) {
      const int row = wcn * 64 + nb * 32 + l31;
      bOff[nb][kh] = 16384 + row * 64 + (((kh * 2 + l32) ^ ((row >> 1) & 3)) << 4);
    }

  f32x16 acc[2][2] = {};

  char* bR = &sm[0];      // read buf  (tile t)
  char* bN = &sm[24576];  // next buf  (tile t+1)
  char* bS = &sm[49152];  // stage buf (tile t+2)

  // prologue: stage tiles 0,1; wait tile 0 (vmcnt(3): tile-1's 3 still out)
  gload_lds16(pa, bR + dA0);
  gload_lds16(pa1, bR + dA1);
  gload_lds16(pb, bR + dB);
  gload_lds16(pa + 32, bN + dA0);
  gload_lds16(pa1 + 32, bN + dA1);
  gload_lds16(pb + 32, bN + dB);
  asm volatile("s_waitcnt vmcnt(3)" ::: "memory");
  __builtin_amdgcn_s_barrier();

  for (int t = 0; t < 128; ++t) {
    if (t <= 125) {  // stage tile t+2 into bS (freed by barrier at end of t-1)
      const int kt = t * 32 + 64;
      gload_lds16(pa + kt, bS + dA0);
      gload_lds16(pa1 + kt, bS + dA1);
      gload_lds16(pb + kt, bS + dB);
    }
    __builtin_amdgcn_s_setprio(1);
#pragma unroll
    for (int kh = 0; kh < 2; ++kh) {
      bf16x8 aF0 = *(const bf16x8*)(bR + aOff[0][kh]);
      bf16x8 aF1 = *(const bf16x8*)(bR + aOff[1][kh]);
      bf16x8 bF0 = *(const bf16x8*)(bR + bOff[0][kh]);
      bf16x8 bF1 = *(const bf16x8*)(bR + bOff[1][kh]);
      acc[0][0] = __builtin_amdgcn_mfma_f32_32x32x16_bf16(aF0, bF0, acc[0][0], 0, 0, 0);
      acc[0][1] = __builtin_amdgcn_mfma_f32_32x32x16_bf16(aF0, bF1, acc[0][1], 0, 0, 0);
      acc[1][0] = __builtin_amdgcn_mfma_f32_32x32x16_bf16(aF1, bF0, acc[1][0], 0, 0, 0);
      acc[1][1] = __builtin_amdgcn_mfma_f32_32x32x16_bf16(aF1, bF1, acc[1][1], 0, 0, 0);
    }
    __builtin_amdgcn_s_setprio(0);
    if (t < 126) {
      asm volatile("s_waitcnt vmcnt(3)" ::: "memory");  // tile t+1 resident
    } else if (t == 126) {
      asm volatile("s_waitcnt vmcnt(0)" ::: "memory");
    }
    if (t < 127) __builtin_amdgcn_s_barrier();
    char* tmp = bR; bR = bN; bN = bS; bS = tmp;  // rotate
  }

  // epilogue: 32x32 C/D layout col = lane&31, row = (r&3) + 8*(r>>2) + 4*(lane>>5)
  float sv[2], bv[2];
#pragma unroll
  for (int nb = 0; nb < 2; ++nb) {
    const int cc = bn + wcn * 64 + nb * 32 + l31;
    sv[nb] = sc[cc];
    bv[nb] = bi[cc];
  }
#pragma unroll
  for (int mb = 0; mb < 2; ++mb) {
    const int rb = bm + wr * 64 + mb * 32 + l32 * 4;
#pragma unroll
    for (int nb = 0; nb < 2; ++nb) {
      const int cc = bn + wcn * 64 + nb * 32 + l31;
      const float s = sv[nb], b = bv[nb];
#pragma unroll
      for (int r = 0; r < 16; ++r) {
        const long long row = rb + (r & 3) + 8 * (r >> 2);
        __builtin_nontemporal_store(acc[mb][nb][r] * s + b,
                                    out + row * NDIM + cc);
      }
    }
  }
}

// ---------- fallback: inline-convert reg-staged GEMM (if ws too small) ----------
__global__ __launch_bounds__(256, 2) void gemm_inline(
    const float* __restrict__ A, const int* __restrict__ W,
    const float* __restrict__ sc, const float* __restrict__ bi,
    float* __restrict__ out) {
  __shared__ unsigned short As[128 * 72];
  __shared__ unsigned short Bs[128 * 72];
  const int tid = threadIdx.x;
  const int lane = tid & 63;
  const int wv = tid >> 6;
  const int wg = (blockIdx.x & 7) * 1024 + (blockIdx.x >> 3);
  const int bm = (wg & 63) * 128;
  const int bn = (wg >> 6) * 128;
  const int wr = (wv >> 1) * 64;
  const int wc = (wv & 1) * 64;
  const int r16 = lane & 15;
  const int g4 = lane >> 4;

  f32x4 acc[4][4] = {};

  const int srow = tid >> 4;
  const int sc4 = (tid & 15) << 2;
  const float* aPtr = A + (long long)(bm + srow) * KDIM + sc4;
  const int* wPtr = W + (long long)(bn + srow) * KDIM + sc4;

  for (int kt = 0; kt < KDIM; kt += 64) {
    float4 av[8];
    int4 wv4[8];
#pragma unroll
    for (int j = 0; j < 8; ++j)
      av[j] = *(const float4*)(aPtr + (long long)j * 16 * KDIM + kt);
#pragma unroll
    for (int j = 0; j < 8; ++j)
      wv4[j] = *(const int4*)(wPtr + (long long)j * 16 * KDIM + kt);
    __syncthreads();
#pragma unroll
    for (int j = 0; j < 8; ++j) {
      ushort4 u;
      u.x = f2bf(av[j].x); u.y = f2bf(av[j].y);
      u.z = f2bf(av[j].z); u.w = f2bf(av[j].w);
      *(ushort4*)&As[(srow + j * 16) * 72 + sc4] = u;
    }
#pragma unroll
    for (int j = 0; j < 8; ++j) {
      ushort4 u;
      u.x = f2bf((float)wv4[j].x); u.y = f2bf((float)wv4[j].y);
      u.z = f2bf((float)wv4[j].z); u.w = f2bf((float)wv4[j].w);
      *(ushort4*)&Bs[(srow + j * 16) * 72 + sc4] = u;
    }
    __syncthreads();
#pragma unroll
    for (int ks = 0; ks < 2; ++ks) {
      bf16x8 aF[4], bF[4];
      const int kofs = ks * 32 + g4 * 8;
#pragma unroll
      for (int m2 = 0; m2 < 4; ++m2)
        aF[m2] = *(const bf16x8*)&As[(wr + m2 * 16 + r16) * 72 + kofs];
#pragma unroll
      for (int n2 = 0; n2 < 4; ++n2)
        bF[n2] = *(const bf16x8*)&Bs[(wc + n2 * 16 + r16) * 72 + kofs];
#pragma unroll
      for (int m2 = 0; m2 < 4; ++m2)
#pragma unroll
        for (int n2 = 0; n2 < 4; ++n2)
          acc[m2][n2] = __builtin_amdgcn_mfma_f32_16x16x32_bf16(
              aF[m2], bF[n2], acc[m2][n2], 0, 0, 0);
    }
  }

  float sv[4], bv[4];
#pragma unroll
  for (int n2 = 0; n2 < 4; ++n2) {
    const int c = bn + wc + n2 * 16 + r16;
    sv[n2] = sc[c];
    bv[n2] = bi[c];
  }
#pragma unroll
  for (int m2 = 0; m2 < 4; ++m2) {
    const int row0 = bm + wr + m2 * 16 + g4 * 4;
#pragma unroll
    for (int n2 = 0; n2 < 4; ++n2) {
      const int c = bn + wc + n2 * 16 + r16;
      float* op = out + (long long)row0 * NDIM + c;
#pragma unroll
      for (int r = 0; r < 4; ++r)
        op[(long long)r * NDIM] = acc[m2][n2][r] * sv[n2] + bv[n2];
    }
  }
}

extern "C" void kernel_launch(void* const* d_in, const int* in_sizes, int n_in,
                              void* d_out, int out_size, void* d_ws, size_t ws_size,
                              hipStream_t stream) {
  const float* A = (const float*)d_in[0];
  const int* W = (const int*)d_in[1];
  const float* sc = (const float*)d_in[2];
  const float* bi = (const float*)d_in[3];
  float* out = (float*)d_out;

  const long long nA = (long long)MDIM * KDIM;
  const long long nW = (long long)NDIM * KDIM;
  const size_t needA = (size_t)nA * sizeof(unsigned short);
  const size_t needW = (size_t)nW * sizeof(unsigned short);

  if (d_ws != nullptr && ws_size >= needA + needW) {
    unsigned short* Ab = (unsigned short*)d_ws;
    unsigned short* Wb = (unsigned short*)((char*)d_ws + needA);
    cvt_a_kernel<<<2048, 256, 0, stream>>>(A, Ab, nA);
    cvt_w_kernel<<<4096, 256, 0, stream>>>(W, Wb, nW);
    gemm_bf16_ov<<<4096, 512, 0, stream>>>(Ab, Wb, sc, bi, out);
  } else {
    gemm_inline<<<8192, 256, 0, stream>>>(A, W, sc, bi, out);
  }
}

// Round 6
// 1120.041 us; speedup vs baseline: 1.4293x; 1.1139x over previous
//
#include <hip/hip_runtime.h>

#define MDIM 8192
#define NDIM 16384
#define KDIM 4096

typedef __bf16 bf16x8 __attribute__((ext_vector_type(8)));
typedef float f32x4 __attribute__((ext_vector_type(4)));
typedef float f32x16 __attribute__((ext_vector_type(16)));

__device__ __forceinline__ unsigned short f2bf(float f) {
  __bf16 h = (__bf16)f;
  return __builtin_bit_cast(unsigned short, h);
}

__device__ __forceinline__ void gload_lds16(const void* g, void* l) {
  __builtin_amdgcn_global_load_lds(
      (const __attribute__((address_space(1))) unsigned int*)g,
      (__attribute__((address_space(3))) unsigned int*)l, 16, 0, 0);
}

// ---------- pass 1a: fp32 -> bf16, tile-panel k-slot-major layout ----------
// Ab ushort layout: [panel(32)][kt(128)][ks(4)][row(256)][j(8)]
//   off = (panel*128 + kt)*8192 + ks*2048 + row*8 + j
// One block = one (panel, kt): 256 threads = 256 rows; thread reads its row's
// 128-B k-chunk (8x float4), writes 4x 16-B (contiguous across lanes).
__global__ __launch_bounds__(256) void cvt_a_kernel(const float* __restrict__ a,
                                                    unsigned short* __restrict__ o) {
  const int panel = blockIdx.x >> 7;  // 0..31
  const int kt = blockIdx.x & 127;    // 0..127
  const int t = threadIdx.x;          // row in panel
  const float* src = a + (long long)(panel * 256 + t) * KDIM + kt * 32;
  union { unsigned short s[32]; uint4 v[4]; } u;
#pragma unroll
  for (int i = 0; i < 8; ++i) {
    float4 x = *(const float4*)(src + i * 4);
    u.s[i * 4 + 0] = f2bf(x.x); u.s[i * 4 + 1] = f2bf(x.y);
    u.s[i * 4 + 2] = f2bf(x.z); u.s[i * 4 + 3] = f2bf(x.w);
  }
  unsigned short* dst = o + ((long long)panel * 128 + kt) * 8192 + t * 8;
#pragma unroll
  for (int ks = 0; ks < 4; ++ks) *(uint4*)(dst + ks * 2048) = u.v[ks];
}

// ---------- pass 1b: int32 (int8 values) -> bf16, tile-panel layout ----------
// Wb ushort layout: [panel(128)][kt(128)][ks(4)][row(128)][j(8)]
//   off = (panel*128 + kt)*4096 + ks*1024 + row*8 + j
__global__ __launch_bounds__(256) void cvt_w_kernel(const int* __restrict__ w,
                                                    unsigned short* __restrict__ o) {
  const int panel = blockIdx.x >> 6;  // 0..127
  const int ktp = blockIdx.x & 63;    // kt pair
  const int t = threadIdx.x;
  const int kt = ktp * 2 + (t >> 7);
  const int row = t & 127;
  const int* src = w + (long long)(panel * 128 + row) * KDIM + kt * 32;
  union { unsigned short s[32]; uint4 v[4]; } u;
#pragma unroll
  for (int i = 0; i < 8; ++i) {
    int4 x = *(const int4*)(src + i * 4);
    u.s[i * 4 + 0] = f2bf((float)x.x); u.s[i * 4 + 1] = f2bf((float)x.y);
    u.s[i * 4 + 2] = f2bf((float)x.z); u.s[i * 4 + 3] = f2bf((float)x.w);
  }
  unsigned short* dst = o + ((long long)panel * 128 + kt) * 4096 + row * 8;
#pragma unroll
  for (int ks = 0; ks < 4; ++ks) *(uint4*)(dst + ks * 1024) = u.v[ks];
}

// ---------- pass 2: 256x128 tile, BK=32, 4 waves x (128x64), 32x32x16 MFMA,
// 3-buf (72 KiB -> 2 blocks/CU), counted vmcnt(6), conflict-free by layout ----
// LDS buf (24576 B): A region [ks(4)][256 rows][16B] = 16 KB at +0;
//                    B region [ks(4)][128 rows][16B] =  8 KB at +16384.
// Frag read = 32 contiguous lanes x 16 B (512 B contiguous) -> every 8-lane
// beat covers all 32 banks exactly once: conflict-free, no XOR needed.
// gl_lds: source contiguous (tile-panel ws layout), dest linear.
__global__ __launch_bounds__(256, 2) void gemm_bf16_v6(
    const unsigned short* __restrict__ Ab, const unsigned short* __restrict__ Wb,
    const float* __restrict__ sc, const float* __restrict__ bi,
    float* __restrict__ out) {
  __shared__ alignas(16) char sm[3 * 24576];
  const int tid = threadIdx.x;
  const int lane = tid & 63;
  const int wv = tid >> 6;   // 0..3
  const int l31 = lane & 31;
  const int l32 = lane >> 5;
  // 2D XCD chunking (verified: FETCH 1.4 GB): XCD owns 8(bm) x 64(bn) rect.
  const int c = blockIdx.x & 7;
  const int l = blockIdx.x >> 3;                 // 0..511
  const int mA = ((c & 3) << 3) + (l & 7);       // 0..31  (A panel / bm tile)
  const int nT = ((c >> 2) << 6) + (l >> 3);     // 0..127 (B panel / bn tile)
  const int bm = mA << 8;
  const int bn = nT << 7;
  const int wr = wv >> 1;   // 0..1 -> A rows wr*128..+128
  const int wcn = wv & 1;   // 0..1 -> B cols wcn*64..+64

  const unsigned short* aBase = Ab + (long long)mA * 128 * 8192;
  const unsigned short* bBase = Wb + (long long)nT * 128 * 4096;

  // frag byte-offsets within a buffer (tile-invariant)
  int aOff[4][2], bOff[2][2];
#pragma unroll
  for (int mb = 0; mb < 4; ++mb)
#pragma unroll
    for (int kh = 0; kh < 2; ++kh)
      aOff[mb][kh] = (kh * 2 + l32) * 4096 + (wr * 128 + mb * 32 + l31) * 16;
#pragma unroll
  for (int nb = 0; nb < 2; ++nb)
#pragma unroll
    for (int kh = 0; kh < 2; ++kh)
      bOff[nb][kh] = 16384 + (kh * 2 + l32) * 2048 + (wcn * 64 + nb * 32 + l31) * 16;

  f32x16 acc[4][2] = {};

  char* bR = &sm[0];      // tile t
  char* bN = &sm[24576];  // tile t+1
  char* bS = &sm[49152];  // tile t+2 (staging)

  auto STAGE = [&](char* buf, int kt) {  // 6 gl_lds per wave
    const unsigned short* as = aBase + (long long)kt * 8192 + wv * 2048 + lane * 8;
    const unsigned short* bs = bBase + (long long)kt * 4096 + wv * 1024 + lane * 8;
#pragma unroll
    for (int i = 0; i < 4; ++i)
      gload_lds16(as + i * 512, buf + wv * 4096 + i * 1024);
#pragma unroll
    for (int i = 0; i < 2; ++i)
      gload_lds16(bs + i * 512, buf + 16384 + wv * 2048 + i * 1024);
  };

  // prologue: tiles 0,1 in flight; tile 0 resident when 6 newest remain
  STAGE(bR, 0);
  STAGE(bN, 1);
  asm volatile("s_waitcnt vmcnt(6)" ::: "memory");
  __builtin_amdgcn_s_barrier();

  for (int t = 0; t < 128; ++t) {
    if (t <= 125) STAGE(bS, t + 2);  // bS = buf of tile t-1, freed at t-1's barrier
    __builtin_amdgcn_s_setprio(1);
#pragma unroll
    for (int kh = 0; kh < 2; ++kh) {
      bf16x8 aF[4], bF[2];
#pragma unroll
      for (int mb = 0; mb < 4; ++mb) aF[mb] = *(const bf16x8*)(bR + aOff[mb][kh]);
#pragma unroll
      for (int nb = 0; nb < 2; ++nb) bF[nb] = *(const bf16x8*)(bR + bOff[nb][kh]);
#pragma unroll
      for (int mb = 0; mb < 4; ++mb)
#pragma unroll
        for (int nb = 0; nb < 2; ++nb)
          acc[mb][nb] = __builtin_amdgcn_mfma_f32_32x32x16_bf16(
              aF[mb], bF[nb], acc[mb][nb], 0, 0, 0);
    }
    __builtin_amdgcn_s_setprio(0);
    if (t < 126) {
      asm volatile("s_waitcnt vmcnt(6)" ::: "memory");  // tile t+1 resident
    } else if (t == 126) {
      asm volatile("s_waitcnt vmcnt(0)" ::: "memory");
    }
    if (t < 127) __builtin_amdgcn_s_barrier();
    char* tmp = bR; bR = bN; bN = bS; bS = tmp;
  }

  // epilogue: 32x32 C/D layout col = lane&31, row = (r&3) + 8*(r>>2) + 4*l32
  float sv[2], bv[2];
#pragma unroll
  for (int nb = 0; nb < 2; ++nb) {
    const int cc = bn + wcn * 64 + nb * 32 + l31;
    sv[nb] = sc[cc];
    bv[nb] = bi[cc];
  }
#pragma unroll
  for (int mb = 0; mb < 4; ++mb) {
    const int rb = bm + wr * 128 + mb * 32 + l32 * 4;
#pragma unroll
    for (int nb = 0; nb < 2; ++nb) {
      const int cc = bn + wcn * 64 + nb * 32 + l31;
      const float s = sv[nb], b = bv[nb];
#pragma unroll
      for (int r = 0; r < 16; ++r) {
        const long long row = rb + (r & 3) + 8 * (r >> 2);
        __builtin_nontemporal_store(acc[mb][nb][r] * s + b, out + row * NDIM + cc);
      }
    }
  }
}

// ---------- fallback: inline-convert reg-staged GEMM (if ws too small) ----------
__global__ __launch_bounds__(256, 2) void gemm_inline(
    const float* __restrict__ A, const int* __restrict__ W,
    const float* __restrict__ sc, const float* __restrict__ bi,
    float* __restrict__ out) {
  __shared__ unsigned short As[128 * 72];
  __shared__ unsigned short Bs[128 * 72];
  const int tid = threadIdx.x;
  const int lane = tid & 63;
  const int wv = tid >> 6;
  const int wg = (blockIdx.x & 7) * 1024 + (blockIdx.x >> 3);
  const int bm = (wg & 63) * 128;
  const int bn = (wg >> 6) * 128;
  const int wr = (wv >> 1) * 64;
  const int wc = (wv & 1) * 64;
  const int r16 = lane & 15;
  const int g4 = lane >> 4;

  f32x4 acc[4][4] = {};

  const int srow = tid >> 4;
  const int sc4 = (tid & 15) << 2;
  const float* aPtr = A + (long long)(bm + srow) * KDIM + sc4;
  const int* wPtr = W + (long long)(bn + srow) * KDIM + sc4;

  for (int kt = 0; kt < KDIM; kt += 64) {
    float4 av[8];
    int4 wv4[8];
#pragma unroll
    for (int j = 0; j < 8; ++j)
      av[j] = *(const float4*)(aPtr + (long long)j * 16 * KDIM + kt);
#pragma unroll
    for (int j = 0; j < 8; ++j)
      wv4[j] = *(const int4*)(wPtr + (long long)j * 16 * KDIM + kt);
    __syncthreads();
#pragma unroll
    for (int j = 0; j < 8; ++j) {
      ushort4 u;
      u.x = f2bf(av[j].x); u.y = f2bf(av[j].y);
      u.z = f2bf(av[j].z); u.w = f2bf(av[j].w);
      *(ushort4*)&As[(srow + j * 16) * 72 + sc4] = u;
    }
#pragma unroll
    for (int j = 0; j < 8; ++j) {
      ushort4 u;
      u.x = f2bf((float)wv4[j].x); u.y = f2bf((float)wv4[j].y);
      u.z = f2bf((float)wv4[j].z); u.w = f2bf((float)wv4[j].w);
      *(ushort4*)&Bs[(srow + j * 16) * 72 + sc4] = u;
    }
    __syncthreads();
#pragma unroll
    for (int ks = 0; ks < 2; ++ks) {
      bf16x8 aF[4], bF[4];
      const int kofs = ks * 32 + g4 * 8;
#pragma unroll
      for (int m2 = 0; m2 < 4; ++m2)
        aF[m2] = *(const bf16x8*)&As[(wr + m2 * 16 + r16) * 72 + kofs];
#pragma unroll
      for (int n2 = 0; n2 < 4; ++n2)
        bF[n2] = *(const bf16x8*)&Bs[(wc + n2 * 16 + r16) * 72 + kofs];
#pragma unroll
      for (int m2 = 0; m2 < 4; ++m2)
#pragma unroll
        for (int n2 = 0; n2 < 4; ++n2)
          acc[m2][n2] = __builtin_amdgcn_mfma_f32_16x16x32_bf16(
              aF[m2], bF[n2], acc[m2][n2], 0, 0, 0);
    }
  }

  float sv[4], bv[4];
#pragma unroll
  for (int n2 = 0; n2 < 4; ++n2) {
    const int c = bn + wc + n2 * 16 + r16;
    sv[n2] = sc[c];
    bv[n2] = bi[c];
  }
#pragma unroll
  for (int m2 = 0; m2 < 4; ++m2) {
    const int row0 = bm + wr + m2 * 16 + g4 * 4;
#pragma unroll
    for (int n2 = 0; n2 < 4; ++n2) {
      const int c = bn + wc + n2 * 16 + r16;
      float* op = out + (long long)row0 * NDIM + c;
#pragma unroll
      for (int r = 0; r < 4; ++r)
        op[(long long)r * NDIM] = acc[m2][n2][r] * sv[n2] + bv[n2];
    }
  }
}

extern "C" void kernel_launch(void* const* d_in, const int* in_sizes, int n_in,
                              void* d_out, int out_size, void* d_ws, size_t ws_size,
                              hipStream_t stream) {
  const float* A = (const float*)d_in[0];
  const int* W = (const int*)d_in[1];
  const float* sc = (const float*)d_in[2];
  const float* bi = (const float*)d_in[3];
  float* out = (float*)d_out;

  const long long nA = (long long)MDIM * KDIM;
  const long long nW = (long long)NDIM * KDIM;
  const size_t needA = (size_t)nA * sizeof(unsigned short);
  const size_t needW = (size_t)nW * sizeof(unsigned short);

  if (d_ws != nullptr && ws_size >= needA + needW) {
    unsigned short* Ab = (unsigned short*)d_ws;
    unsigned short* Wb = (unsigned short*)((char*)d_ws + needA);
    cvt_a_kernel<<<4096, 256, 0, stream>>>(A, Ab);
    cvt_w_kernel<<<8192, 256, 0, stream>>>(W, Wb);
    gemm_bf16_v6<<<4096, 256, 0, stream>>>(Ab, Wb, sc, bi, out);
  } else {
    gemm_inline<<<8192, 256, 0, stream>>>(A, W, sc, bi, out);
  }
}

// Round 7
// 1092.731 us; speedup vs baseline: 1.4650x; 1.0250x over previous
//
#include <hip/hip_runtime.h>

#define MDIM 8192
#define NDIM 16384
#define KDIM 4096

typedef __bf16 bf16x8 __attribute__((ext_vector_type(8)));
typedef float f32x4 __attribute__((ext_vector_type(4)));

__device__ __forceinline__ unsigned short f2bf(float f) {
  __bf16 h = (__bf16)f;
  return __builtin_bit_cast(unsigned short, h);
}

__device__ __forceinline__ void gload_lds16(const void* g, void* l) {
  __builtin_amdgcn_global_load_lds(
      (const __attribute__((address_space(1))) unsigned int*)g,
      (__attribute__((address_space(3))) unsigned int*)l, 16, 0, 0);
}

// ======== ws layouts (ks-plane-major; all GEMM LDS traffic contiguous) ======
// Ab: [mtile(32)][kt64(64)][ks(8)][row(256)][8]   piece (kq) = ks 4q..4q+3 = 16KB
// Wb: [ntile(64)][kt64(64)][ks(8)][row(256)][8]
// (ks = k/8 within the BK=64 tile; cell = 8 bf16 = 16B)

// ---------- pass 1a: fp32 -> bf16 into Ab (LDS-bounced transpose) ----------
__global__ __launch_bounds__(256) void cvt_a_kernel(const float* __restrict__ a,
                                                    unsigned short* __restrict__ o) {
  __shared__ unsigned short lds[4 * 2056];  // 4 ks-planes, +8 pad each
  const int mt = blockIdx.x >> 7;           // 0..31
  const int kt = (blockIdx.x >> 1) & 63;    // 0..63
  const int kq = blockIdx.x & 1;            // 0..1
  const int tid = threadIdx.x;
#pragma unroll
  for (int j = 0; j < 8; ++j) {
    const int idx = tid + j * 256;          // 0..2047
    const int row = idx >> 3;               // 0..255
    const int kc = idx & 7;                 // float4-chunk in row (32 k)
    float4 v = *(const float4*)(a + (long long)(mt * 256 + row) * KDIM +
                                kt * 64 + kq * 32 + kc * 4);
    ushort4 u;
    u.x = f2bf(v.x); u.y = f2bf(v.y); u.z = f2bf(v.z); u.w = f2bf(v.w);
    *(ushort4*)&lds[(kc >> 1) * 2056 + row * 8 + (kc & 1) * 4] = u;
  }
  __syncthreads();
  unsigned short* dst = o + (((long long)mt * 64 + kt) << 14) + (kq << 13);
#pragma unroll
  for (int j = 0; j < 4; ++j) {
    const int c = tid + j * 256;            // 0..1023 cells
    *(uint4*)(dst + c * 8) = *(const uint4*)&lds[(c >> 8) * 2056 + (c & 255) * 8];
  }
}

// ---------- pass 1b: int32 (int8 values) -> bf16 into Wb ----------
__global__ __launch_bounds__(256) void cvt_w_kernel(const int* __restrict__ w,
                                                    unsigned short* __restrict__ o) {
  __shared__ unsigned short lds[4 * 2056];
  const int nt = blockIdx.x >> 7;           // 0..63
  const int kt = (blockIdx.x >> 1) & 63;
  const int kq = blockIdx.x & 1;
  const int tid = threadIdx.x;
#pragma unroll
  for (int j = 0; j < 8; ++j) {
    const int idx = tid + j * 256;
    const int row = idx >> 3;
    const int kc = idx & 7;
    int4 v = *(const int4*)(w + (long long)(nt * 256 + row) * KDIM +
                            kt * 64 + kq * 32 + kc * 4);
    ushort4 u;
    u.x = f2bf((float)v.x); u.y = f2bf((float)v.y);
    u.z = f2bf((float)v.z); u.w = f2bf((float)v.w);
    *(ushort4*)&lds[(kc >> 1) * 2056 + row * 8 + (kc & 1) * 4] = u;
  }
  __syncthreads();
  unsigned short* dst = o + (((long long)nt * 64 + kt) << 14) + (kq << 13);
#pragma unroll
  for (int j = 0; j < 4; ++j) {
    const int c = tid + j * 256;
    *(uint4*)(dst + c * 8) = *(const uint4*)&lds[(c >> 8) * 2056 + (c & 255) * 8];
  }
}

// ---------- pass 2: m201-style 8-phase 256x256 GEMM, BK=64, dbuf 128KiB ------
// 8 waves (2M x 4N), wave = 128x64, mfma_f32_16x16x32_bf16.
// Buf (64KB): A = [ks(8)][row(256)][16B] at +0; B = same at +32768.
// Pieces (16KB = 2 gl_lds/thread): A-kq0(ks0-3), A-kq1(ks4-7), B-kq0, B-kq1.
// Region last-read -> stage slot (race-free across the phase end-barrier):
//   A-kq0: ph1 -> stage(t+2) at ph2     B-kq0: ph2 -> stage(t+2) at ph3
//   A-kq1: ph3 -> stage(t+2) at ph4     B-kq1: ph4 -> stage(t+1) at ph1
// Gate: end-of-tile vmcnt(6) (3 newest pieces in flight) lands B-kq1(t+1) and
// all older => tile t+1 fully resident. Tail: t==62 -> vmcnt(0).
__global__ __launch_bounds__(512, 2) void gemm_bf16_8ph(
    const unsigned short* __restrict__ Ab, const unsigned short* __restrict__ Wb,
    const float* __restrict__ sc, const float* __restrict__ bi,
    float* __restrict__ out) {
  __shared__ alignas(16) char sm[2 * 65536];
  const int tid = threadIdx.x;
  const int lane = tid & 63;
  const int wv = tid >> 6;
  const int r16 = lane & 15;
  const int g4 = lane >> 4;
  const int wr = wv >> 2;   // 0..1 -> rows wr*128
  const int wc = wv & 3;    // 0..3 -> cols wc*64
  // 2D XCD chunking: XCD owns 8(m) x 32(n) tile rect; 2048 blocks
  const int c = blockIdx.x & 7;
  const int l = blockIdx.x >> 3;              // 0..255
  const int mA = ((c & 3) << 3) + (l & 7);    // 0..31
  const int nT = ((c >> 2) << 5) + (l >> 3);  // 0..63
  const int bm = mA << 8;
  const int bn = nT << 8;

  // frag byte-offsets (tile-invariant); each read = 16 lanes x 16B contiguous
  int aOff[2][8], bOff[2][4];
#pragma unroll
  for (int kk = 0; kk < 2; ++kk) {
#pragma unroll
    for (int m = 0; m < 8; ++m)
      aOff[kk][m] = (kk * 4 + g4) * 4096 + (wr * 128 + m * 16 + r16) * 16;
#pragma unroll
    for (int n = 0; n < 4; ++n)
      bOff[kk][n] = 32768 + (kk * 4 + g4) * 4096 + (wc * 64 + n * 16 + r16) * 16;
  }

  f32x4 acc[8][4] = {};

  auto STAGE_A = [&](int tt, int q) {
    const unsigned short* s =
        Ab + (((long long)mA * 64 + tt) << 14) + (q << 13) + (tid << 3);
    char* d = sm + ((tt & 1) << 16) + (q << 14) + (tid << 4);
    gload_lds16(s, d);
    gload_lds16(s + 4096, d + 8192);
  };
  auto STAGE_B = [&](int tt, int q) {
    const unsigned short* s =
        Wb + (((long long)nT * 64 + tt) << 14) + (q << 13) + (tid << 3);
    char* d = sm + ((tt & 1) << 16) + 32768 + (q << 14) + (tid << 4);
    gload_lds16(s, d);
    gload_lds16(s + 4096, d + 8192);
  };

  // prologue (issue-age order): tile0 pieces + tile1 {A0,B0,A1}; wait tile 0
  STAGE_A(0, 0); STAGE_B(0, 0); STAGE_A(0, 1); STAGE_B(0, 1);
  STAGE_A(1, 0); STAGE_B(1, 0); STAGE_A(1, 1);
  asm volatile("s_waitcnt vmcnt(6)" ::: "memory");
  __builtin_amdgcn_s_barrier();

  for (int t = 0; t < 64; ++t) {
    char* base = sm + ((t & 1) << 16);
    bf16x8 aF[8], bF[2];

    // -------- phase 1: quadrant (kk0, n0-1); stage B-kq1(t+1) --------
#pragma unroll
    for (int m = 0; m < 8; ++m) aF[m] = *(const bf16x8*)(base + aOff[0][m]);
    bF[0] = *(const bf16x8*)(base + bOff[0][0]);
    bF[1] = *(const bf16x8*)(base + bOff[0][1]);
    if (t + 1 < 64) STAGE_B(t + 1, 1);
    __builtin_amdgcn_s_barrier();
    asm volatile("s_waitcnt lgkmcnt(0)" ::: "memory");
    __builtin_amdgcn_sched_barrier(0);
    __builtin_amdgcn_s_setprio(1);
#pragma unroll
    for (int m = 0; m < 8; ++m) {
      acc[m][0] = __builtin_amdgcn_mfma_f32_16x16x32_bf16(aF[m], bF[0], acc[m][0], 0, 0, 0);
      acc[m][1] = __builtin_amdgcn_mfma_f32_16x16x32_bf16(aF[m], bF[1], acc[m][1], 0, 0, 0);
    }
    __builtin_amdgcn_s_setprio(0);
    __builtin_amdgcn_s_barrier();

    // -------- phase 2: quadrant (kk0, n2-3); stage A-kq0(t+2) --------
    bF[0] = *(const bf16x8*)(base + bOff[0][2]);
    bF[1] = *(const bf16x8*)(base + bOff[0][3]);
    if (t + 2 < 64) STAGE_A(t + 2, 0);
    __builtin_amdgcn_s_barrier();
    asm volatile("s_waitcnt lgkmcnt(0)" ::: "memory");
    __builtin_amdgcn_sched_barrier(0);
    __builtin_amdgcn_s_setprio(1);
#pragma unroll
    for (int m = 0; m < 8; ++m) {
      acc[m][2] = __builtin_amdgcn_mfma_f32_16x16x32_bf16(aF[m], bF[0], acc[m][2], 0, 0, 0);
      acc[m][3] = __builtin_amdgcn_mfma_f32_16x16x32_bf16(aF[m], bF[1], acc[m][3], 0, 0, 0);
    }
    __builtin_amdgcn_s_setprio(0);
    __builtin_amdgcn_s_barrier();

    // -------- phase 3: quadrant (kk1, n0-1); stage B-kq0(t+2) --------
#pragma unroll
    for (int m = 0; m < 8; ++m) aF[m] = *(const bf16x8*)(base + aOff[1][m]);
    bF[0] = *(const bf16x8*)(base + bOff[1][0]);
    bF[1] = *(const bf16x8*)(base + bOff[1][1]);
    if (t + 2 < 64) STAGE_B(t + 2, 0);
    __builtin_amdgcn_s_barrier();
    asm volatile("s_waitcnt lgkmcnt(0)" ::: "memory");
    __builtin_amdgcn_sched_barrier(0);
    __builtin_amdgcn_s_setprio(1);
#pragma unroll
    for (int m = 0; m < 8; ++m) {
      acc[m][0] = __builtin_amdgcn_mfma_f32_16x16x32_bf16(aF[m], bF[0], acc[m][0], 0, 0, 0);
      acc[m][1] = __builtin_amdgcn_mfma_f32_16x16x32_bf16(aF[m], bF[1], acc[m][1], 0, 0, 0);
    }
    __builtin_amdgcn_s_setprio(0);
    __builtin_amdgcn_s_barrier();

    // -------- phase 4: quadrant (kk1, n2-3); stage A-kq1(t+2); gate --------
    bF[0] = *(const bf16x8*)(base + bOff[1][2]);
    bF[1] = *(const bf16x8*)(base + bOff[1][3]);
    if (t + 2 < 64) STAGE_A(t + 2, 1);
    __builtin_amdgcn_s_barrier();
    asm volatile("s_waitcnt lgkmcnt(0)" ::: "memory");
    __builtin_amdgcn_sched_barrier(0);
    __builtin_amdgcn_s_setprio(1);
#pragma unroll
    for (int m = 0; m < 8; ++m) {
      acc[m][2] = __builtin_amdgcn_mfma_f32_16x16x32_bf16(aF[m], bF[0], acc[m][2], 0, 0, 0);
      acc[m][3] = __builtin_amdgcn_mfma_f32_16x16x32_bf16(aF[m], bF[1], acc[m][3], 0, 0, 0);
    }
    __builtin_amdgcn_s_setprio(0);
    if (t <= 61) {
      asm volatile("s_waitcnt vmcnt(6)" ::: "memory");
    } else if (t == 62) {
      asm volatile("s_waitcnt vmcnt(0)" ::: "memory");
    }
    if (t < 63) __builtin_amdgcn_s_barrier();
  }

  // epilogue: 16x16 C/D layout col = lane&15, row = (lane>>4)*4 + r
  float sv[4], bv[4];
#pragma unroll
  for (int n = 0; n < 4; ++n) {
    const int cc = bn + wc * 64 + n * 16 + r16;
    sv[n] = sc[cc];
    bv[n] = bi[cc];
  }
#pragma unroll
  for (int m = 0; m < 8; ++m) {
    const int row0 = bm + wr * 128 + m * 16 + g4 * 4;
#pragma unroll
    for (int n = 0; n < 4; ++n) {
      const int cc = bn + wc * 64 + n * 16 + r16;
      float* op = out + (long long)row0 * NDIM + cc;
#pragma unroll
      for (int r = 0; r < 4; ++r)
        __builtin_nontemporal_store(acc[m][n][r] * sv[n] + bv[n],
                                    op + (long long)r * NDIM);
    }
  }
}

// ---------- fallback: inline-convert reg-staged GEMM (if ws too small) ----------
__global__ __launch_bounds__(256, 2) void gemm_inline(
    const float* __restrict__ A, const int* __restrict__ W,
    const float* __restrict__ sc, const float* __restrict__ bi,
    float* __restrict__ out) {
  __shared__ unsigned short As[128 * 72];
  __shared__ unsigned short Bs[128 * 72];
  const int tid = threadIdx.x;
  const int lane = tid & 63;
  const int wv = tid >> 6;
  const int wg = (blockIdx.x & 7) * 1024 + (blockIdx.x >> 3);
  const int bm = (wg & 63) * 128;
  const int bn = (wg >> 6) * 128;
  const int wr = (wv >> 1) * 64;
  const int wc = (wv & 1) * 64;
  const int r16 = lane & 15;
  const int g4 = lane >> 4;

  f32x4 acc[4][4] = {};

  const int srow = tid >> 4;
  const int sc4 = (tid & 15) << 2;
  const float* aPtr = A + (long long)(bm + srow) * KDIM + sc4;
  const int* wPtr = W + (long long)(bn + srow) * KDIM + sc4;

  for (int kt = 0; kt < KDIM; kt += 64) {
    float4 av[8];
    int4 wv4[8];
#pragma unroll
    for (int j = 0; j < 8; ++j)
      av[j] = *(const float4*)(aPtr + (long long)j * 16 * KDIM + kt);
#pragma unroll
    for (int j = 0; j < 8; ++j)
      wv4[j] = *(const int4*)(wPtr + (long long)j * 16 * KDIM + kt);
    __syncthreads();
#pragma unroll
    for (int j = 0; j < 8; ++j) {
      ushort4 u;
      u.x = f2bf(av[j].x); u.y = f2bf(av[j].y);
      u.z = f2bf(av[j].z); u.w = f2bf(av[j].w);
      *(ushort4*)&As[(srow + j * 16) * 72 + sc4] = u;
    }
#pragma unroll
    for (int j = 0; j < 8; ++j) {
      ushort4 u;
      u.x = f2bf((float)wv4[j].x); u.y = f2bf((float)wv4[j].y);
      u.z = f2bf((float)wv4[j].z); u.w = f2bf((float)wv4[j].w);
      *(ushort4*)&Bs[(srow + j * 16) * 72 + sc4] = u;
    }
    __syncthreads();
#pragma unroll
    for (int ks = 0; ks < 2; ++ks) {
      bf16x8 aF[4], bF[4];
      const int kofs = ks * 32 + g4 * 8;
#pragma unroll
      for (int m2 = 0; m2 < 4; ++m2)
        aF[m2] = *(const bf16x8*)&As[(wr + m2 * 16 + r16) * 72 + kofs];
#pragma unroll
      for (int n2 = 0; n2 < 4; ++n2)
        bF[n2] = *(const bf16x8*)&Bs[(wc + n2 * 16 + r16) * 72 + kofs];
#pragma unroll
      for (int m2 = 0; m2 < 4; ++m2)
#pragma unroll
        for (int n2 = 0; n2 < 4; ++n2)
          acc[m2][n2] = __builtin_amdgcn_mfma_f32_16x16x32_bf16(
              aF[m2], bF[n2], acc[m2][n2], 0, 0, 0);
    }
  }

  float sv[4], bv[4];
#pragma unroll
  for (int n2 = 0; n2 < 4; ++n2) {
    const int c = bn + wc + n2 * 16 + r16;
    sv[n2] = sc[c];
    bv[n2] = bi[c];
  }
#pragma unroll
  for (int m2 = 0; m2 < 4; ++m2) {
    const int row0 = bm + wr + m2 * 16 + g4 * 4;
#pragma unroll
    for (int n2 = 0; n2 < 4; ++n2) {
      const int c = bn + wc + n2 * 16 + r16;
      float* op = out + (long long)row0 * NDIM + c;
#pragma unroll
      for (int r = 0; r < 4; ++r)
        op[(long long)r * NDIM] = acc[m2][n2][r] * sv[n2] + bv[n2];
    }
  }
}

extern "C" void kernel_launch(void* const* d_in, const int* in_sizes, int n_in,
                              void* d_out, int out_size, void* d_ws, size_t ws_size,
                              hipStream_t stream) {
  const float* A = (const float*)d_in[0];
  const int* W = (const int*)d_in[1];
  const float* sc = (const float*)d_in[2];
  const float* bi = (const float*)d_in[3];
  float* out = (float*)d_out;

  const long long nA = (long long)MDIM * KDIM;
  const long long nW = (long long)NDIM * KDIM;
  const size_t needA = (size_t)nA * sizeof(unsigned short);
  const size_t needW = (size_t)nW * sizeof(unsigned short);

  if (d_ws != nullptr && ws_size >= needA + needW) {
    unsigned short* Ab = (unsigned short*)d_ws;
    unsigned short* Wb = (unsigned short*)((char*)d_ws + needA);
    cvt_a_kernel<<<4096, 256, 0, stream>>>(A, Ab);
    cvt_w_kernel<<<8192, 256, 0, stream>>>(W, Wb);
    gemm_bf16_8ph<<<2048, 512, 0, stream>>>(Ab, Wb, sc, bi, out);
  } else {
    gemm_inline<<<8192, 256, 0, stream>>>(A, W, sc, bi, out);
  }
}

// Round 8
// 1054.957 us; speedup vs baseline: 1.5175x; 1.0358x over previous
//
#include <hip/hip_runtime.h>

#define MDIM 8192
#define NDIM 16384
#define KDIM 4096

typedef __bf16 bf16x8 __attribute__((ext_vector_type(8)));
typedef float f32x4 __attribute__((ext_vector_type(4)));
typedef float f32x16 __attribute__((ext_vector_type(16)));

__device__ __forceinline__ unsigned short f2bf(float f) {
  __bf16 h = (__bf16)f;
  return __builtin_bit_cast(unsigned short, h);
}

__device__ __forceinline__ void gload_lds16(const void* g, void* l) {
  __builtin_amdgcn_global_load_lds(
      (const __attribute__((address_space(1))) unsigned int*)g,
      (__attribute__((address_space(3))) unsigned int*)l, 16, 0, 0);
}

// ======== ws layouts (ks-plane-major; all GEMM LDS traffic contiguous) ======
// Ab: [mtile(32)][kt64(64)][ks(8)][row(256)][8]   piece (kq) = ks 4q..4q+3 = 16KB
// Wb: [ntile(64)][kt64(64)][ks(8)][row(256)][8]
// (ks = k/8 within the BK=64 tile; cell = 8 bf16 = 16B)

// ---------- pass 1a: fp32 -> bf16 into Ab (LDS-bounced transpose) ----------
__global__ __launch_bounds__(256) void cvt_a_kernel(const float* __restrict__ a,
                                                    unsigned short* __restrict__ o) {
  __shared__ unsigned short lds[4 * 2056];  // 4 ks-planes, +8 pad each
  const int mt = blockIdx.x >> 7;           // 0..31
  const int kt = (blockIdx.x >> 1) & 63;    // 0..63
  const int kq = blockIdx.x & 1;            // 0..1
  const int tid = threadIdx.x;
#pragma unroll
  for (int j = 0; j < 8; ++j) {
    const int idx = tid + j * 256;          // 0..2047
    const int row = idx >> 3;               // 0..255
    const int kc = idx & 7;                 // float4-chunk in row (32 k)
    float4 v = *(const float4*)(a + (long long)(mt * 256 + row) * KDIM +
                                kt * 64 + kq * 32 + kc * 4);
    ushort4 u;
    u.x = f2bf(v.x); u.y = f2bf(v.y); u.z = f2bf(v.z); u.w = f2bf(v.w);
    *(ushort4*)&lds[(kc >> 1) * 2056 + row * 8 + (kc & 1) * 4] = u;
  }
  __syncthreads();
  unsigned short* dst = o + (((long long)mt * 64 + kt) << 14) + (kq << 13);
#pragma unroll
  for (int j = 0; j < 4; ++j) {
    const int c = tid + j * 256;            // 0..1023 cells
    *(uint4*)(dst + c * 8) = *(const uint4*)&lds[(c >> 8) * 2056 + (c & 255) * 8];
  }
}

// ---------- pass 1b: int32 (int8 values) -> bf16 into Wb ----------
__global__ __launch_bounds__(256) void cvt_w_kernel(const int* __restrict__ w,
                                                    unsigned short* __restrict__ o) {
  __shared__ unsigned short lds[4 * 2056];
  const int nt = blockIdx.x >> 7;           // 0..63
  const int kt = (blockIdx.x >> 1) & 63;
  const int kq = blockIdx.x & 1;
  const int tid = threadIdx.x;
#pragma unroll
  for (int j = 0; j < 8; ++j) {
    const int idx = tid + j * 256;
    const int row = idx >> 3;
    const int kc = idx & 7;
    int4 v = *(const int4*)(w + (long long)(nt * 256 + row) * KDIM +
                            kt * 64 + kq * 32 + kc * 4);
    ushort4 u;
    u.x = f2bf((float)v.x); u.y = f2bf((float)v.y);
    u.z = f2bf((float)v.z); u.w = f2bf((float)v.w);
    *(ushort4*)&lds[(kc >> 1) * 2056 + row * 8 + (kc & 1) * 4] = u;
  }
  __syncthreads();
  unsigned short* dst = o + (((long long)nt * 64 + kt) << 14) + (kq << 13);
#pragma unroll
  for (int j = 0; j < 4; ++j) {
    const int c = tid + j * 256;
    *(uint4*)(dst + c * 8) = *(const uint4*)&lds[(c >> 8) * 2056 + (c & 255) * 8];
  }
}

// ---------- pass 2: 256x256 tile, BK=64, dbuf 128KiB, 8 waves x (128x64),
// mfma_f32_32x32x16_bf16, 2 relaxed phases/tile (compiler-scheduled lgkm),
// counted vmcnt(4), conflict-free by ws layout. ----
// Buf (64KB): A = [ks(8)][row(256)][16B] at +0; B = same at +32768.
// Phase A: stage kq1(t+1)->obuf (last read: phase B of t-1, freed at its final
//   barrier); compute kk=0,1 (planes ks0-3); barrier.
// Phase B: stage kq0(t+2)->cur ks0-3 (last read: phase A, freed at its
//   barrier); compute kk=2,3; vmcnt(4); barrier.
// Gate: vmcnt(4) keeps only phase-B's 4 loads in flight => kq1(t+1) and
// kq0(t+1) (issued phase B of t-1) have landed: tile t+1 resident.
__global__ __launch_bounds__(512, 2) void gemm_bf16_v8(
    const unsigned short* __restrict__ Ab, const unsigned short* __restrict__ Wb,
    const float* __restrict__ sc, const float* __restrict__ bi,
    float* __restrict__ out) {
  __shared__ alignas(16) char sm[2 * 65536];
  const int tid = threadIdx.x;
  const int lane = tid & 63;
  const int wv = tid >> 6;
  const int l31 = lane & 31;
  const int l32 = lane >> 5;
  const int wr = wv >> 2;   // 0..1 -> rows wr*128
  const int wc = wv & 3;    // 0..3 -> cols wc*64
  // 2D XCD chunking (verified r7: FETCH ~0.85 GB)
  const int c = blockIdx.x & 7;
  const int l = blockIdx.x >> 3;              // 0..255
  const int mA = ((c & 3) << 3) + (l & 7);    // 0..31
  const int nT = ((c >> 2) << 5) + (l >> 3);  // 0..63
  const int bm = mA << 8;
  const int bn = nT << 8;

  // frag byte-offsets (tile-invariant); each read = 32 lanes x 16B contiguous
  int aOff[4][4], bOff[4][2];
#pragma unroll
  for (int kk = 0; kk < 4; ++kk) {
#pragma unroll
    for (int mb = 0; mb < 4; ++mb)
      aOff[kk][mb] = (kk * 2 + l32) * 4096 + (wr * 128 + mb * 32 + l31) * 16;
#pragma unroll
    for (int nb = 0; nb < 2; ++nb)
      bOff[kk][nb] = 32768 + (kk * 2 + l32) * 4096 + (wc * 64 + nb * 32 + l31) * 16;
  }

  f32x16 acc[4][2] = {};

  const unsigned short* a0 = Ab + (((long long)mA * 64) << 14) + (tid << 3);
  const unsigned short* b0 = Wb + (((long long)nT * 64) << 14) + (tid << 3);
  const int t16 = tid << 4;

  // prologue: kq0(0), kq1(0), kq0(1) = 12 loads; 4 newest = kq0(1)
  gload_lds16(a0, sm + t16);
  gload_lds16(a0 + 4096, sm + 8192 + t16);
  gload_lds16(b0, sm + 32768 + t16);
  gload_lds16(b0 + 4096, sm + 40960 + t16);
  gload_lds16(a0 + 8192, sm + 16384 + t16);
  gload_lds16(a0 + 12288, sm + 24576 + t16);
  gload_lds16(b0 + 8192, sm + 49152 + t16);
  gload_lds16(b0 + 12288, sm + 57344 + t16);
  gload_lds16(a0 + 16384, sm + 65536 + t16);
  gload_lds16(a0 + 20480, sm + 65536 + 8192 + t16);
  gload_lds16(b0 + 16384, sm + 65536 + 32768 + t16);
  gload_lds16(b0 + 20480, sm + 65536 + 40960 + t16);
  asm volatile("s_waitcnt vmcnt(4)" ::: "memory");
  __builtin_amdgcn_s_barrier();

  const unsigned short* pAq1 = a0 + 16384 + 8192;  // kq1 of tile 1
  const unsigned short* pBq1 = b0 + 16384 + 8192;
  const unsigned short* pAq0 = a0 + 32768;         // kq0 of tile 2
  const unsigned short* pBq0 = b0 + 32768;

  auto PHASE = [&](const char* cur, const int kkA, const int kkB) {
    bf16x8 aF0[4], aF1[4], bF0[2], bF1[2];
#pragma unroll
    for (int mb = 0; mb < 4; ++mb) aF0[mb] = *(const bf16x8*)(cur + aOff[kkA][mb]);
#pragma unroll
    for (int nb = 0; nb < 2; ++nb) bF0[nb] = *(const bf16x8*)(cur + bOff[kkA][nb]);
#pragma unroll
    for (int mb = 0; mb < 4; ++mb) aF1[mb] = *(const bf16x8*)(cur + aOff[kkB][mb]);
#pragma unroll
    for (int nb = 0; nb < 2; ++nb) bF1[nb] = *(const bf16x8*)(cur + bOff[kkB][nb]);
#pragma unroll
    for (int mb = 0; mb < 4; ++mb)
#pragma unroll
      for (int nb = 0; nb < 2; ++nb)
        acc[mb][nb] = __builtin_amdgcn_mfma_f32_32x32x16_bf16(
            aF0[mb], bF0[nb], acc[mb][nb], 0, 0, 0);
#pragma unroll
    for (int mb = 0; mb < 4; ++mb)
#pragma unroll
      for (int nb = 0; nb < 2; ++nb)
        acc[mb][nb] = __builtin_amdgcn_mfma_f32_32x32x16_bf16(
            aF1[mb], bF1[nb], acc[mb][nb], 0, 0, 0);
  };

  auto TILE = [&](int t, char* cur, char* obuf) {
    // ---- phase A: stage kq1(t+1) -> obuf; compute kk 0,1 ----
    if (t + 1 < 64) {
      gload_lds16(pAq1, obuf + 16384 + t16);
      gload_lds16(pAq1 + 4096, obuf + 24576 + t16);
      gload_lds16(pBq1, obuf + 49152 + t16);
      gload_lds16(pBq1 + 4096, obuf + 57344 + t16);
    }
    __builtin_amdgcn_s_setprio(1);
    PHASE(cur, 0, 1);
    __builtin_amdgcn_s_setprio(0);
    __builtin_amdgcn_s_barrier();
    // ---- phase B: stage kq0(t+2) -> cur; compute kk 2,3 ----
    if (t + 2 < 64) {
      gload_lds16(pAq0, cur + t16);
      gload_lds16(pAq0 + 4096, cur + 8192 + t16);
      gload_lds16(pBq0, cur + 32768 + t16);
      gload_lds16(pBq0 + 4096, cur + 40960 + t16);
    }
    __builtin_amdgcn_s_setprio(1);
    PHASE(cur, 2, 3);
    __builtin_amdgcn_s_setprio(0);
    if (t <= 61) {
      asm volatile("s_waitcnt vmcnt(4)" ::: "memory");
    } else if (t == 62) {
      asm volatile("s_waitcnt vmcnt(0)" ::: "memory");
    }
    if (t < 63) __builtin_amdgcn_s_barrier();
    pAq1 += 16384; pBq1 += 16384; pAq0 += 16384; pBq0 += 16384;
  };

  for (int t = 0; t < 64; t += 2) {
    TILE(t, sm, sm + 65536);
    TILE(t + 1, sm + 65536, sm);
  }

  // epilogue: 32x32 C/D layout col = lane&31, row = (r&3) + 8*(r>>2) + 4*l32
  float sv[2], bv[2];
#pragma unroll
  for (int nb = 0; nb < 2; ++nb) {
    const int cc = bn + wc * 64 + nb * 32 + l31;
    sv[nb] = sc[cc];
    bv[nb] = bi[cc];
  }
#pragma unroll
  for (int mb = 0; mb < 4; ++mb) {
    const int rb = bm + wr * 128 + mb * 32 + l32 * 4;
#pragma unroll
    for (int nb = 0; nb < 2; ++nb) {
      const int cc = bn + wc * 64 + nb * 32 + l31;
      const float s = sv[nb], b = bv[nb];
#pragma unroll
      for (int r = 0; r < 16; ++r) {
        const long long row = rb + (r & 3) + 8 * (r >> 2);
        __builtin_nontemporal_store(acc[mb][nb][r] * s + b, out + row * NDIM + cc);
      }
    }
  }
}

// ---------- fallback: inline-convert reg-staged GEMM (if ws too small) ----------
__global__ __launch_bounds__(256, 2) void gemm_inline(
    const float* __restrict__ A, const int* __restrict__ W,
    const float* __restrict__ sc, const float* __restrict__ bi,
    float* __restrict__ out) {
  __shared__ unsigned short As[128 * 72];
  __shared__ unsigned short Bs[128 * 72];
  const int tid = threadIdx.x;
  const int lane = tid & 63;
  const int wv = tid >> 6;
  const int wg = (blockIdx.x & 7) * 1024 + (blockIdx.x >> 3);
  const int bm = (wg & 63) * 128;
  const int bn = (wg >> 6) * 128;
  const int wr = (wv >> 1) * 64;
  const int wc = (wv & 1) * 64;
  const int r16 = lane & 15;
  const int g4 = lane >> 4;

  f32x4 acc[4][4] = {};

  const int srow = tid >> 4;
  const int sc4 = (tid & 15) << 2;
  const float* aPtr = A + (long long)(bm + srow) * KDIM + sc4;
  const int* wPtr = W + (long long)(bn + srow) * KDIM + sc4;

  for (int kt = 0; kt < KDIM; kt += 64) {
    float4 av[8];
    int4 wv4[8];
#pragma unroll
    for (int j = 0; j < 8; ++j)
      av[j] = *(const float4*)(aPtr + (long long)j * 16 * KDIM + kt);
#pragma unroll
    for (int j = 0; j < 8; ++j)
      wv4[j] = *(const int4*)(wPtr + (long long)j * 16 * KDIM + kt);
    __syncthreads();
#pragma unroll
    for (int j = 0; j < 8; ++j) {
      ushort4 u;
      u.x = f2bf(av[j].x); u.y = f2bf(av[j].y);
      u.z = f2bf(av[j].z); u.w = f2bf(av[j].w);
      *(ushort4*)&As[(srow + j * 16) * 72 + sc4] = u;
    }
#pragma unroll
    for (int j = 0; j < 8; ++j) {
      ushort4 u;
      u.x = f2bf((float)wv4[j].x); u.y = f2bf((float)wv4[j].y);
      u.z = f2bf((float)wv4[j].z); u.w = f2bf((float)wv4[j].w);
      *(ushort4*)&Bs[(srow + j * 16) * 72 + sc4] = u;
    }
    __syncthreads();
#pragma unroll
    for (int ks = 0; ks < 2; ++ks) {
      bf16x8 aF[4], bF[4];
      const int kofs = ks * 32 + g4 * 8;
#pragma unroll
      for (int m2 = 0; m2 < 4; ++m2)
        aF[m2] = *(const bf16x8*)&As[(wr + m2 * 16 + r16) * 72 + kofs];
#pragma unroll
      for (int n2 = 0; n2 < 4; ++n2)
        bF[n2] = *(const bf16x8*)&Bs[(wc + n2 * 16 + r16) * 72 + kofs];
#pragma unroll
      for (int m2 = 0; m2 < 4; ++m2)
#pragma unroll
        for (int n2 = 0; n2 < 4; ++n2)
          acc[m2][n2] = __builtin_amdgcn_mfma_f32_16x16x32_bf16(
              aF[m2], bF[n2], acc[m2][n2], 0, 0, 0);
    }
  }

  float sv[4], bv[4];
#pragma unroll
  for (int n2 = 0; n2 < 4; ++n2) {
    const int c = bn + wc + n2 * 16 + r16;
    sv[n2] = sc[c];
    bv[n2] = bi[c];
  }
#pragma unroll
  for (int m2 = 0; m2 < 4; ++m2) {
    const int row0 = bm + wr + m2 * 16 + g4 * 4;
#pragma unroll
    for (int n2 = 0; n2 < 4; ++n2) {
      const int c = bn + wc + n2 * 16 + r16;
      float* op = out + (long long)row0 * NDIM + c;
#pragma unroll
      for (int r = 0; r < 4; ++r)
        op[(long long)r * NDIM] = acc[m2][n2][r] * sv[n2] + bv[n2];
    }
  }
}

extern "C" void kernel_launch(void* const* d_in, const int* in_sizes, int n_in,
                              void* d_out, int out_size, void* d_ws, size_t ws_size,
                              hipStream_t stream) {
  const float* A = (const float*)d_in[0];
  const int* W = (const int*)d_in[1];
  const float* sc = (const float*)d_in[2];
  const float* bi = (const float*)d_in[3];
  float* out = (float*)d_out;

  const long long nA = (long long)MDIM * KDIM;
  const long long nW = (long long)NDIM * KDIM;
  const size_t needA = (size_t)nA * sizeof(unsigned short);
  const size_t needW = (size_t)nW * sizeof(unsigned short);

  if (d_ws != nullptr && ws_size >= needA + needW) {
    unsigned short* Ab = (unsigned short*)d_ws;
    unsigned short* Wb = (unsigned short*)((char*)d_ws + needA);
    cvt_a_kernel<<<4096, 256, 0, stream>>>(A, Ab);
    cvt_w_kernel<<<8192, 256, 0, stream>>>(W, Wb);
    gemm_bf16_v8<<<2048, 512, 0, stream>>>(Ab, Wb, sc, bi, out);
  } else {
    gemm_inline<<<8192, 256, 0, stream>>>(A, W, sc, bi, out);
  }
}